// Round 4
// baseline (581.337 us; speedup 1.0000x reference)
//
#include <hip/hip_runtime.h>
#include <hip/hip_bf16.h>

#define D_IN   4096
#define D_OUT  4096
#define NTOK   8192
#define SEQ    2048
#define ER     64
#define NSLICE 16          // K-split for lora stage-1

typedef float        f32x4  __attribute__((ext_vector_type(4)));
typedef float        f32x16 __attribute__((ext_vector_type(16)));
typedef unsigned int u32x4  __attribute__((ext_vector_type(4)));
typedef unsigned int u32x2  __attribute__((ext_vector_type(2)));
typedef short        s16x8  __attribute__((ext_vector_type(8)));
typedef __bf16       bf16x8 __attribute__((ext_vector_type(8)));
typedef _Float16     f16x8  __attribute__((ext_vector_type(8)));
typedef _Float16     f16x4  __attribute__((ext_vector_type(4)));

// ---------------- bf16 helpers (lora stage-1 numerics) ----------------------
__device__ inline unsigned f2bf1(float f){
    unsigned u = __builtin_bit_cast(unsigned, f);
    return (u + 0x7fffu + ((u >> 16) & 1u)) >> 16;
}
__device__ inline unsigned pack2(float a, float b){ return f2bf1(a) | (f2bf1(b) << 16); }
__device__ inline f32x4 mfma_bf16(s16x8 a, s16x8 b, f32x4 c){
    return __builtin_amdgcn_mfma_f32_16x16x32_bf16(
        __builtin_bit_cast(bf16x8, a), __builtin_bit_cast(bf16x8, b), c, 0, 0, 0);
}
// ---------------- fp16 32x32x16 (main GEMM) ---------------------------------
__device__ inline f32x16 mfma32(s16x8 a, s16x8 b, f32x16 c){
    return __builtin_amdgcn_mfma_f32_32x32x16_f16(
        __builtin_bit_cast(f16x8, a), __builtin_bit_cast(f16x8, b), c, 0, 0, 0);
}

// ---------------------------------------------------------------------------
// K0: w f32 -> fp16.
// ---------------------------------------------------------------------------
__global__ __launch_bounds__(256) void convert_w_kernel(
    const float* __restrict__ w, _Float16* __restrict__ wh)
{
    size_t i = ((size_t)blockIdx.x * 256 + threadIdx.x) * 8;
    f32x4 a = *(const f32x4*)(w + i);
    f32x4 c = *(const f32x4*)(w + i + 4);
    f16x8 h;
    #pragma unroll
    for (int j = 0; j < 4; ++j){ h[j] = (_Float16)a[j]; h[4+j] = (_Float16)c[j]; }
    *(f16x8*)(wh + i) = h;
}

// ---------------------------------------------------------------------------
// K1 (stage 1): per (m-tile 64, k-slice 256) block, single shot:
//   - convert x slice -> xh (fp16) and LDS (bf16)
//   - partial c[64][64] = x_slice @ lA_slice^T   (bf16 MFMA, fp16 partials)
//   - partial logits [64][8] (img 0..3, txt 4..7) on wave 0
// ---------------------------------------------------------------------------
__global__ __launch_bounds__(256) void lora_part_kernel(
    const float* __restrict__ x,
    const float* __restrict__ wr_img, const float* __restrict__ wr_txt,
    const float* __restrict__ lA,
    _Float16* __restrict__ xh, _Float16* __restrict__ pc, float* __restrict__ plg)
{
    __shared__ short xs[64][264];        // 264-short rows: bank-spread

    const int tid  = threadIdx.x;
    const int lane = tid & 63;
    const int wid  = tid >> 6;
    const int mt   = blockIdx.x & 127;
    const int sl   = blockIdx.x >> 7;
    const int t0   = mt * 64;
    const int kb   = sl * 256;

    // ---- x slice: load f32, write fp16 to xh, write bf16 to LDS
    #pragma unroll
    for (int j = 0; j < 8; ++j){
        int q   = tid + j * 256;         // 0..2047 chunks of 8 floats
        int row = q >> 5, cc = q & 31;
        const float* src = x + (size_t)(t0 + row) * D_IN + kb + cc * 8;
        f32x4 v0 = *(const f32x4*)src;
        f32x4 v1 = *(const f32x4*)(src + 4);
        f16x8 h;
        #pragma unroll
        for (int jj = 0; jj < 4; ++jj){ h[jj] = (_Float16)v0[jj]; h[4+jj] = (_Float16)v1[jj]; }
        *(f16x8*)(xh + (size_t)(t0 + row) * D_IN + kb + cc * 8) = h;
        *(u32x4*)&xs[row][cc * 8] = (u32x4){pack2(v0[0],v0[1]), pack2(v0[2],v0[3]),
                                            pack2(v1[0],v1[1]), pack2(v1[2],v1[3])};
    }
    __syncthreads();

    const int fr = lane & 15, fq = lane >> 4;
    f32x4 acc[4]  = {{0,0,0,0},{0,0,0,0},{0,0,0,0},{0,0,0,0}};
    f32x4 accR[4] = {{0,0,0,0},{0,0,0,0},{0,0,0,0},{0,0,0,0}};

    // B operands straight from global (L2-hot): er = wid*16+fr
    const float* bp = lA + (size_t)(wid * 16 + fr) * D_IN + kb + fq * 8;
    const float* rp = (fr < 4) ? wr_img + (size_t)fr * D_IN + kb + fq * 8
                               : wr_txt + (size_t)(fr - 4) * D_IN + kb + fq * 8;

    #pragma unroll
    for (int ks = 0; ks < 8; ++ks){
        f32x4 b0 = *(const f32x4*)(bp + ks * 32);
        f32x4 b1 = *(const f32x4*)(bp + ks * 32 + 4);
        s16x8 bw = __builtin_bit_cast(s16x8,
            (u32x4){pack2(b0[0],b0[1]), pack2(b0[2],b0[3]),
                    pack2(b1[0],b1[1]), pack2(b1[2],b1[3])});
        s16x8 bR = __builtin_bit_cast(s16x8, (u32x4){0u,0u,0u,0u});
        if (wid == 0 && fr < 8){
            f32x4 r0 = *(const f32x4*)(rp + ks * 32);
            f32x4 r1 = *(const f32x4*)(rp + ks * 32 + 4);
            bR = __builtin_bit_cast(s16x8,
                (u32x4){pack2(r0[0],r0[1]), pack2(r0[2],r0[3]),
                        pack2(r1[0],r1[1]), pack2(r1[2],r1[3])});
        }
        #pragma unroll
        for (int mi = 0; mi < 4; ++mi){
            s16x8 a = *(const s16x8*)&xs[mi * 16 + fr][ks * 32 + fq * 8];
            acc[mi] = mfma_bf16(a, bw, acc[mi]);
            if (wid == 0) accR[mi] = mfma_bf16(a, bR, accR[mi]);
        }
    }

    _Float16* pcb = pc + ((size_t)sl * NTOK + t0) * ER;
    #pragma unroll
    for (int mi = 0; mi < 4; ++mi)
        #pragma unroll
        for (int r = 0; r < 4; ++r)
            pcb[(size_t)(mi * 16 + fq * 4 + r) * ER + wid * 16 + fr] = (_Float16)acc[mi][r];

    if (wid == 0 && fr < 8){
        float* pb = plg + ((size_t)sl * NTOK + t0) * 8;
        #pragma unroll
        for (int mi = 0; mi < 4; ++mi)
            #pragma unroll
            for (int r = 0; r < 4; ++r)
                pb[(size_t)(mi * 16 + fq * 4 + r) * 8 + fr] = accR[mi][r];
    }
}

// ---------------------------------------------------------------------------
// K2 (stage 2): reduce 16 slices, router-select + softmax + gate*2, -> c_h fp16
// ---------------------------------------------------------------------------
__global__ __launch_bounds__(256) void lora_gate_kernel(
    const _Float16* __restrict__ pc, const float* __restrict__ plg,
    const float* __restrict__ br_img, const float* __restrict__ br_txt,
    _Float16* __restrict__ c_h)
{
    const int tid = threadIdx.x;
    const int row = blockIdx.x * 16 + (tid >> 4);
    const int erq = (tid & 15) * 4;

    float s0=0.f, s1=0.f, s2=0.f, s3=0.f;
    float lg0=0,lg1=0,lg2=0,lg3=0,lg4=0,lg5=0,lg6=0,lg7=0;
    #pragma unroll
    for (int sl = 0; sl < NSLICE; ++sl){
        f16x4 v = *(const f16x4*)(pc + ((size_t)sl * NTOK + row) * ER + erq);
        s0 += (float)v[0]; s1 += (float)v[1]; s2 += (float)v[2]; s3 += (float)v[3];
        const float* q = plg + ((size_t)sl * NTOK + row) * 8;
        f32x4 a = *(const f32x4*)q;
        f32x4 b = *(const f32x4*)(q + 4);
        lg0 += a[0]; lg1 += a[1]; lg2 += a[2]; lg3 += a[3];
        lg4 += b[0]; lg5 += b[1]; lg6 += b[2]; lg7 += b[3];
    }
    const bool img = (row & (SEQ - 1)) < 32;
    const float* br = img ? br_img : br_txt;
    float l0 = (img ? lg0 : lg4) + br[0];
    float l1 = (img ? lg1 : lg5) + br[1];
    float l2 = (img ? lg2 : lg6) + br[2];
    float l3 = (img ? lg3 : lg7) + br[3];
    float mx = fmaxf(fmaxf(l0, l1), fmaxf(l2, l3));
    float e0 = expf(l0 - mx), e1 = expf(l1 - mx), e2 = expf(l2 - mx), e3 = expf(l3 - mx);
    float inv = 2.0f / (e0 + e1 + e2 + e3);
    const int e = erq >> 4;
    float g = (e == 0 ? e0 : e == 1 ? e1 : e == 2 ? e2 : e3) * inv;

    f16x4 o;
    o[0] = (_Float16)(s0 * g); o[1] = (_Float16)(s1 * g);
    o[2] = (_Float16)(s2 * g); o[3] = (_Float16)(s3 * g);
    *(f16x4*)(c_h + (size_t)row * ER + erq) = o;
}

// ---------------------------------------------------------------------------
// K3: main GEMM. Same 8-phase/quadrant schedule + vmcnt slots as R3, MFMA
// switched to 32x32x16 f16 (4061 vs 3378 FLOP/cyc). BM=BN=256, BK=64,
// 8 waves (2Mx4N), wave tile 128x64 = 4x2 tiles of 32x32.
// Epilogue: LoRA second projection (c_h @ Bt, K=64, 32x32 MFMA) + bias.
// ---------------------------------------------------------------------------
#define REG_A0 0
#define REG_A1 16384
#define REG_B0 32768
#define REG_B1 49152
#define BUFSZ  65536

__device__ inline void gload16(const void* g, void* l){
    __builtin_amdgcn_global_load_lds(
        (const __attribute__((address_space(1))) unsigned*)g,
        (__attribute__((address_space(3))) unsigned*)l, 16, 0, 0);
}
__device__ inline void stage_half_tile(const _Float16* gbase, char* lds, int tid){
    #pragma unroll
    for (int j = 0; j < 2; ++j){
        int q   = j*512 + tid;
        int row = q >> 3;
        int c7  = (q & 7) ^ (row & 7);
        gload16(gbase + (size_t)row * D_IN + c7*8, lds + q*16);
    }
}
// 32x32x16 fragment: lane covers row (lane&31), k-chunk kh=(lane>>5); K=64 -> ks 0..3
__device__ inline s16x8 ldsfrag32(const char* region, int row, int ks, int kh){
    int ch = ((ks << 1) | kh) ^ (row & 7);
    return *(const s16x8*)(region + row*128 + ch*16);
}
#define BAR()   __builtin_amdgcn_s_barrier()
#define LGKM0() asm volatile("s_waitcnt lgkmcnt(0)" ::: "memory")
#define PRIO(x) __builtin_amdgcn_s_setprio(x)

__global__ __launch_bounds__(512, 2) void main_gemm_kernel(
    const _Float16* __restrict__ xh, const _Float16* __restrict__ wh,
    const float* __restrict__ bias, const float* __restrict__ lB,
    const _Float16* __restrict__ c_h, float* __restrict__ out)
{
    __shared__ __align__(16) char smem[2 * BUFSZ];

    const int tid  = threadIdx.x;
    const int lane = tid & 63;
    const int wid  = tid >> 6;
    const int wr   = wid >> 2;           // 0..1  (128-row half)
    const int wc   = wid & 3;            // 0..3  (64-col strip)
    const int l31  = lane & 31;
    const int kh   = lane >> 5;

    const int bid = blockIdx.x;                      // 512 blocks: 32 mt x 16 nt
    const int swz = (bid & 7) * 64 + (bid >> 3);     // XCD swizzle (512 % 8 == 0)
    const int mt  = swz & 31, nt = swz >> 5;
    const int m0  = mt * 256, n0 = nt * 256;

    const _Float16* gA0 = xh + (size_t)m0 * D_IN;
    const _Float16* gA1 = gA0 + (size_t)128 * D_IN;
    const _Float16* gB0 = wh + (size_t)n0 * D_IN;
    const _Float16* gB1 = gB0 + (size_t)128 * D_IN;

    // prologue: tile0 full, tile1 {B0,A0,A1}
    stage_half_tile(gA0,      smem + REG_A0,         tid);
    stage_half_tile(gA1,      smem + REG_A1,         tid);
    stage_half_tile(gB0,      smem + REG_B0,         tid);
    stage_half_tile(gB1,      smem + REG_B1,         tid);
    stage_half_tile(gB0 + 64, smem + BUFSZ + REG_B0, tid);
    stage_half_tile(gA0 + 64, smem + BUFSZ + REG_A0, tid);
    stage_half_tile(gA1 + 64, smem + BUFSZ + REG_A1, tid);
    asm volatile("s_waitcnt vmcnt(6)" ::: "memory");
    BAR();

    f32x16 acc[4][2];
    #pragma unroll
    for (int tr = 0; tr < 4; ++tr)
        #pragma unroll
        for (int tc = 0; tc < 2; ++tc)
            #pragma unroll
            for (int v = 0; v < 16; ++v) acc[tr][tc][v] = 0.f;

    const int bcol0 = (wc & 1) * 64;

    for (int it = 0; it < 32; ++it){
        const bool pred = (it < 31);
        #pragma unroll
        for (int hf = 0; hf < 2; ++hf){
            char* buf  = smem + hf * BUFSZ;          // tile 2it+hf
            char* obuf = smem + (hf ^ 1) * BUFSZ;
            const char* Ab = buf + wr * 16384;                 // my 128-row A half
            const char* Bb = buf + REG_B0 + (wc >> 1) * 16384; // my B region
            const size_t kP0 = (size_t)(2*it + 1 + hf) * 64;
            const size_t kN  = (size_t)(2*it + 2 + hf) * 64;
            const bool  prP0 = (hf == 0) ? true : pred;

            s16x8 af[2][4], blo[4], bhi[4];
            // ---- P0: (Alo, Blo); 12 reads; stage other-buf B1
            #pragma unroll
            for (int tr = 0; tr < 2; ++tr)
                #pragma unroll
                for (int ks = 0; ks < 4; ++ks)
                    af[tr][ks] = ldsfrag32(Ab, tr*32 + l31, ks, kh);
            #pragma unroll
            for (int ks = 0; ks < 4; ++ks)
                blo[ks] = ldsfrag32(Bb, bcol0 + l31, ks, kh);
            if (prP0) stage_half_tile(gB1 + kP0, obuf + REG_B1, tid);
            BAR(); LGKM0(); PRIO(1);
            #pragma unroll
            for (int tr = 0; tr < 2; ++tr)
                #pragma unroll
                for (int ks = 0; ks < 4; ++ks)
                    acc[tr][0] = mfma32(af[tr][ks], blo[ks], acc[tr][0]);
            PRIO(0); BAR();
            // ---- P1: (Alo, Bhi); 4 reads
            #pragma unroll
            for (int ks = 0; ks < 4; ++ks)
                bhi[ks] = ldsfrag32(Bb, bcol0 + 32 + l31, ks, kh);
            BAR(); LGKM0(); PRIO(1);
            #pragma unroll
            for (int tr = 0; tr < 2; ++tr)
                #pragma unroll
                for (int ks = 0; ks < 4; ++ks)
                    acc[tr][1] = mfma32(af[tr][ks], bhi[ks], acc[tr][1]);
            PRIO(0); BAR();
            // ---- P2: (Ahi, Bhi); 8 reads; stage cur-buf B0
            #pragma unroll
            for (int tr = 0; tr < 2; ++tr)
                #pragma unroll
                for (int ks = 0; ks < 4; ++ks)
                    af[tr][ks] = ldsfrag32(Ab, 64 + tr*32 + l31, ks, kh);
            if (pred) stage_half_tile(gB0 + kN, buf + REG_B0, tid);
            BAR(); LGKM0(); PRIO(1);
            #pragma unroll
            for (int tr = 0; tr < 2; ++tr)
                #pragma unroll
                for (int ks = 0; ks < 4; ++ks)
                    acc[2+tr][1] = mfma32(af[tr][ks], bhi[ks], acc[2+tr][1]);
            PRIO(0); BAR();
            // ---- P3: (Ahi, Blo); 0 reads; stage cur-buf A0+A1
            if (pred){
                stage_half_tile(gA0 + kN, buf + REG_A0, tid);
                stage_half_tile(gA1 + kN, buf + REG_A1, tid);
            }
            BAR(); PRIO(1);
            #pragma unroll
            for (int tr = 0; tr < 2; ++tr)
                #pragma unroll
                for (int ks = 0; ks < 4; ++ks)
                    acc[2+tr][0] = mfma32(af[tr][ks], blo[ks], acc[2+tr][0]);
            PRIO(0);
            if (pred)           asm volatile("s_waitcnt vmcnt(6)" ::: "memory");
            else if (hf == 0)   asm volatile("s_waitcnt vmcnt(0)" ::: "memory");
            BAR();
        }
    }

    // ---- epilogue: stage c_h[256][64] @0 (fp16 copy), Bt[256][64] @32K -----
    #pragma unroll
    for (int k2 = 0; k2 < 4; ++k2){
        int q = tid + k2*512;              // 0..2047 chunks of 16B
        int row = q >> 3, cc = q & 7;
        s16x8 v = *(const s16x8*)(c_h + (size_t)(m0 + row) * ER + cc*8);
        *(s16x8*)(smem + row*128 + ((cc ^ (row & 7)))*16) = v;
    }
    #pragma unroll
    for (int k2 = 0; k2 < 4; ++k2){
        int q = tid + k2*512;
        int row = q >> 3, cc = q & 7;
        int e = cc >> 1, r0 = (cc & 1) * 8;
        const float* bsrc = lB + (size_t)e * D_OUT * 16 + (size_t)(n0 + row) * 16 + r0;
        f32x4 v0 = *(const f32x4*)bsrc;
        f32x4 v1 = *(const f32x4*)(bsrc + 4);
        f16x8 h;
        #pragma unroll
        for (int j = 0; j < 4; ++j){ h[j] = (_Float16)v0[j]; h[4+j] = (_Float16)v1[j]; }
        *(s16x8*)(smem + 32768 + row*128 + ((cc ^ (row & 7)))*16) = __builtin_bit_cast(s16x8, h);
    }
    __syncthreads();

    {
        s16x8 btf[2][4];
        #pragma unroll
        for (int tc = 0; tc < 2; ++tc)
            #pragma unroll
            for (int ks = 0; ks < 4; ++ks)
                btf[tc][ks] = ldsfrag32(smem + 32768, wc*64 + tc*32 + l31, ks, kh);
        #pragma unroll
        for (int tr = 0; tr < 4; ++tr){
            s16x8 cf[4];
            #pragma unroll
            for (int ks = 0; ks < 4; ++ks)
                cf[ks] = ldsfrag32(smem, wr*128 + tr*32 + l31, ks, kh);
            #pragma unroll
            for (int tc = 0; tc < 2; ++tc)
                #pragma unroll
                for (int ks = 0; ks < 4; ++ks)
                    acc[tr][tc] = mfma32(cf[ks], btf[tc][ks], acc[tr][tc]);
        }
    }

    // ---- bias + store (C map: col=lane&31, row=(reg&3)+8*(reg>>2)+4*kh) ----
    const int colb = n0 + wc*64 + l31;
    const int rowb = m0 + wr*128 + kh*4;
    #pragma unroll
    for (int tc = 0; tc < 2; ++tc){
        const float bb = bias[colb + tc*32];
        #pragma unroll
        for (int tr = 0; tr < 4; ++tr)
            #pragma unroll
            for (int g = 0; g < 4; ++g)
                #pragma unroll
                for (int r = 0; r < 4; ++r)
                    out[(size_t)(rowb + tr*32 + g*8 + r) * D_OUT + colb + tc*32]
                        = acc[tr][tc][g*4 + r] + bb;
    }
}

// ---------------------------------------------------------------------------
extern "C" void kernel_launch(void* const* d_in, const int* in_sizes, int n_in,
                              void* d_out, int out_size, void* d_ws, size_t ws_size,
                              hipStream_t stream)
{
    const float* x      = (const float*)d_in[0];
    const float* w_base = (const float*)d_in[1];
    const float* b_base = (const float*)d_in[2];
    const float* wr_img = (const float*)d_in[3];
    const float* br_img = (const float*)d_in[4];
    const float* wr_txt = (const float*)d_in[5];
    const float* br_txt = (const float*)d_in[6];
    const float* lA     = (const float*)d_in[7];
    const float* lB     = (const float*)d_in[8];
    float* out = (float*)d_out;

    char* ws = (char*)d_ws;
    _Float16* c_h = (_Float16*)ws;                          // 1 MB
    _Float16* xh  = (_Float16*)(ws + (size_t)( 2 << 20));   // 64 MB
    _Float16* wh  = (_Float16*)(ws + (size_t)(66 << 20));   // 32 MB
    _Float16* pc  = (_Float16*)(ws + (size_t)(98 << 20));   // 16 MB partial c
    float*    plg = (float*)   (ws + (size_t)(114 << 20));  // 4 MB partial logits

    lora_part_kernel<<<dim3(128 * NSLICE), dim3(256), 0, stream>>>(
        x, wr_img, wr_txt, lA, xh, pc, plg);
    convert_w_kernel<<<dim3(8192), dim3(256), 0, stream>>>(w_base, wh);
    lora_gate_kernel<<<dim3(NTOK / 16), dim3(256), 0, stream>>>(
        pc, plg, br_img, br_txt, c_h);
    main_gemm_kernel<<<dim3(512), dim3(512), 0, stream>>>(
        xh, wh, b_base, lB, c_h, out);
}